// Round 8
// baseline (389.780 us; speedup 1.0000x reference)
//
#include <hip/hip_runtime.h>
#include <math.h>

#define C 256
#define H 64
#define W 64
#define B 32
#define HW (H*W)
#define EPS 1e-5f
#define LSTR2 256  // shorts per row of the [w][ci] LDS tiles (512 B)

typedef __attribute__((ext_vector_type(8))) short short8;   // 8 bf16
typedef __attribute__((ext_vector_type(4))) short short4v;  // 4 bf16
typedef __attribute__((ext_vector_type(4))) float f32x4;

// Branchless gelu, exact-mode accurate: Abramowitz-Stegun 7.1.26 erf
// (max abs err 1.5e-7 -> gelu abs err <= ~1e-6, far under bf16 rounding).
__device__ __forceinline__ float gelu_fast(float z) {
    float a = fabsf(z) * 0.70710678f;
    float t = __frcp_rn(1.f + 0.3275911f * a);
    float p = t * (0.254829592f + t * (-0.284496736f + t * (1.421413741f +
              t * (-1.453152027f + t * 1.061405429f))));
    float e = __expf(-a * a);
    float q = 0.5f * fabsf(z) * p * e;
    return fmaxf(z, 0.f) - q;
}
__device__ __forceinline__ short f2bf(float f) {
    union { float f; unsigned u; } v; v.f = f;
    unsigned r = v.u + 0x7fffu + ((v.u >> 16) & 1u);
    return (short)(r >> 16);
}
__device__ __forceinline__ float bf2f(short s) {
    union { unsigned u; float f; } v; v.u = ((unsigned)(unsigned short)s) << 16;
    return v.f;
}
// XOR-swizzle (short-index units, 8-short groups) for the [w][ci] tiles.
__device__ __forceinline__ int swz8(int w) {
    return (((w & 7) ^ ((w >> 3) & 7)) << 3);
}
// XCD-aware remap for grid (2H, B): each XCD gets 16 consecutive half-rows
// (= 8 consecutive h, both halves) per b -> conv h-halo rows are L2-hits.
// Rotated across b so every XCD sees every batch. Bijective.
__device__ __forceinline__ void swz_hb2(int bx, int by, int& h, int& wbase, int& b) {
    int wg  = bx + (by << 7);        // 0..4095
    int xcd = wg & 7, lin = wg >> 3; // lin 0..511
    b = lin >> 4;                    // == by
    int j = lin & 15;                // == bx>>3
    int unit = (((xcd + b) & 7) << 4) + j;   // 0..127 half-row index
    h = unit >> 1;
    wbase = (unit & 1) * 32;
}

__global__ __launch_bounds__(256) void pool_kernel(const float* __restrict__ x,
                                                   float* __restrict__ pooled) {
    int bc = blockIdx.x;
    const float4* p4 = (const float4*)(x + (size_t)bc * HW);
    int t = threadIdx.x;
    float s = 0.f;
    for (int i = t; i < HW/4; i += 256) {
        float4 v = p4[i];
        s += v.x + v.y + v.z + v.w;
    }
    for (int off = 32; off > 0; off >>= 1) s += __shfl_down(s, off, 64);
    __shared__ float wsum[4];
    if ((t & 63) == 0) wsum[t >> 6] = s;
    __syncthreads();
    if (t == 0) pooled[bc] = (wsum[0]+wsum[1]+wsum[2]+wsum[3]) * (1.f/HW);
}

// blocks 0..191: pack 6 C*C fp32 matrices into bf16 MFMA fragments:
//   mat 0: pw0_hi  1: pw1_hi  2: pw2_hi  3: e2k_hi  4: pw2_lo  5: e2k_lo
// fragment chunk (kt,mt): lane holds M[o=mt*16+(lane&15)][ci=kt*32+(lane>>4)*8+j].
// block 192: fold BN into conv weights + sc/sh tables.
// block 193: routing (argmax logit; softmax/temp monotone, top-1 weight == 1).
__global__ __launch_bounds__(256) void prep_kernel(
    const float* __restrict__ s0, const float* __restrict__ s1,
    const float* __restrict__ s2, const float* __restrict__ s3,
    const float* __restrict__ e0k, const float* __restrict__ e1k,
    const float* __restrict__ g0, const float* __restrict__ b0,
    const float* __restrict__ m0, const float* __restrict__ v0,
    const float* __restrict__ g1, const float* __restrict__ b1,
    const float* __restrict__ m1, const float* __restrict__ v1,
    const float* __restrict__ g2, const float* __restrict__ b2,
    const float* __restrict__ m2, const float* __restrict__ v2,
    const float* __restrict__ pooled, const float* __restrict__ rw,
    const float* __restrict__ rb, int* __restrict__ idx,
    short* __restrict__ apackAll, float* __restrict__ kf0, float* __restrict__ kf1,
    float* __restrict__ scAll, float* __restrict__ shAll)
{
    if (blockIdx.x < 192) {
        int gid = blockIdx.x * 256 + threadIdx.x;       // 0..49151
        int mat = gid >> 13;                            // 0..5
        int c   = gid & 8191;
        int lane = c & 63;
        int ktmt = c >> 6;
        int mt = ktmt & 15, kt = ktmt >> 4;
        int o  = mt*16 + (lane & 15);
        int ci = kt*32 + (lane >> 4)*8;
        const float* src = (mat == 0) ? s0 : (mat == 1) ? s1 :
                           (mat == 2 || mat == 4) ? s2 : s3;
        bool lo = (mat >= 4);
        const float* p = src + o*C + ci;
        short8 v;
#pragma unroll
        for (int j = 0; j < 8; ++j) {
            float f = p[j];
            short hj = f2bf(f);
            v[j] = lo ? f2bf(f - bf2f(hj)) : hj;
        }
        *(short8*)&apackAll[(size_t)gid * 8] = v;
    } else if (blockIdx.x == 192) {
        int t = threadIdx.x;   // = ci
        {
            float s = g0[t] / sqrtf(v0[t] + EPS);
            scAll[t] = s; shAll[t] = b0[t] - m0[t]*s;
#pragma unroll
            for (int j = 0; j < 9; ++j) kf0[t*12+j] = e0k[t*9+j]*s;
            kf0[t*12+9] = 0.f; kf0[t*12+10] = 0.f; kf0[t*12+11] = 0.f;
        }
        {
            float s = g1[t] / sqrtf(v1[t] + EPS);
            scAll[C+t] = s; shAll[C+t] = b1[t] - m1[t]*s;
#pragma unroll
            for (int j = 0; j < 9; ++j) kf1[t*12+j] = e1k[t*9+j]*s;
            kf1[t*12+9] = 0.f; kf1[t*12+10] = 0.f; kf1[t*12+11] = 0.f;
        }
        {
            float s = g2[t] / sqrtf(v2[t] + EPS);
            scAll[2*C+t] = s; shAll[2*C+t] = b2[t] - m2[t]*s;
        }
    } else {
        // routing block — single UNIFORM barrier (no divergent __syncthreads)
        __shared__ float lg[3*B];
        int t = threadIdx.x;
        int e = t >> 6, lane = t & 63;
        if (e < 3) {
            for (int b = 0; b < B; ++b) {
                const float* p = pooled + b*C;
                const float* w = rw + e*C;
                float s = 0.f;
#pragma unroll
                for (int i = 0; i < 4; ++i) s += p[lane + i*64] * w[lane + i*64];
                for (int off = 32; off > 0; off >>= 1) s += __shfl_down(s, off, 64);
                if (lane == 0) lg[b*3 + e] = s + rb[e];
            }
        }
        __syncthreads();
        if (t < B) {
            float l0 = lg[t*3], l1 = lg[t*3+1], l2 = lg[t*3+2];
            int best = 0; float bv = l0;
            if (l1 > bv) { bv = l1; best = 1; }
            if (l2 > bv) { bv = l2; best = 2; }
            idx[t] = best;
        }
    }
}

// Register buffer for one conv iteration (all indices compile-time -> stays in VGPRs)
struct ConvBuf {
    float fr[3][16];
    float4 k0, k1;
    float shv;
};

// Half-row conv (32 px), dilation DIL, software-pipelined (load i+1 before comp i).
// Writes gelu(BN(conv)) bf16 TRANSPOSED into lds[wl][ci^swz], wl = w-wbase in 0..31.
// Halo taps (incl. across the half-row boundary) come from GLOBAL memory -> no
// cross-block coupling; per-output arithmetic identical to the full-row kernel.
template<int DIL>
__device__ __forceinline__ void conv_half_t(const float* __restrict__ x,
                                            const float* __restrict__ kf,
                                            const float* __restrict__ sh,
                                            short* __restrict__ lds,
                                            int b, int h, int wbase, int t) {
    const int strip = t & 3;          // 4 strips x 8 w
    const int w0l = strip * 8;
    const int w0 = wbase + w0l;       // global w of strip start
    const int cib = t >> 2;           // 0..63
    const bool hasL = (w0 > 0), hasR = (w0 + 8 < W);
    bool rv[3];
    int yy[3];
#pragma unroll
    for (int ky = 0; ky < 3; ++ky) {
        int y = h + (ky - 1) * DIL;
        rv[ky] = ((unsigned)y < H);      // wave-uniform
        yy[ky] = rv[ky] ? y : 0;         // safe row for predicated load
    }

    auto load = [&](ConvBuf& Bv, int iter) {
        int ci = iter*64 + cib;
        const float* xpl = x + (size_t)(b*C + ci) * HW;
#pragma unroll
        for (int ky = 0; ky < 3; ++ky) {
            const float* row = xpl + yy[ky]*W;
            float4 fa = (rv[ky] && hasL) ? *(const float4*)(row + w0 - 4) : float4{0,0,0,0};
            float4 fb = rv[ky] ? *(const float4*)(row + w0)     : float4{0,0,0,0};
            float4 fc = rv[ky] ? *(const float4*)(row + w0 + 4) : float4{0,0,0,0};
            float4 fd = (rv[ky] && hasR) ? *(const float4*)(row + w0 + 8) : float4{0,0,0,0};
            Bv.fr[ky][0]=fa.x;  Bv.fr[ky][1]=fa.y;  Bv.fr[ky][2]=fa.z;  Bv.fr[ky][3]=fa.w;
            Bv.fr[ky][4]=fb.x;  Bv.fr[ky][5]=fb.y;  Bv.fr[ky][6]=fb.z;  Bv.fr[ky][7]=fb.w;
            Bv.fr[ky][8]=fc.x;  Bv.fr[ky][9]=fc.y;  Bv.fr[ky][10]=fc.z; Bv.fr[ky][11]=fc.w;
            Bv.fr[ky][12]=fd.x; Bv.fr[ky][13]=fd.y; Bv.fr[ky][14]=fd.z; Bv.fr[ky][15]=fd.w;
        }
        Bv.k0 = *(const float4*)(kf + ci*12);
        Bv.k1 = *(const float4*)(kf + ci*12 + 4);
        Bv.shv = sh[ci];
    };
    auto comp = [&](ConvBuf& Bv, int iter) {
        int ci = iter*64 + cib;
        float wk[9] = {Bv.k0.x,Bv.k0.y,Bv.k0.z,Bv.k0.w,
                       Bv.k1.x,Bv.k1.y,Bv.k1.z,Bv.k1.w, kf[ci*12+8]};
        float acc8[8] = {0,0,0,0,0,0,0,0};
#pragma unroll
        for (int ky = 0; ky < 3; ++ky) {
            if (rv[ky]) {
#pragma unroll
                for (int kx = 0; kx < 3; ++kx) {
                    float wv = wk[ky*3+kx];
                    const int base = 4 + (kx - 1)*DIL;   // compile-time
#pragma unroll
                    for (int j = 0; j < 8; ++j) acc8[j] += wv * Bv.fr[ky][base + j];
                }
            }
        }
        float shv = Bv.shv;
#pragma unroll
        for (int j = 0; j < 8; ++j) {
            int wl = w0l + j;
            lds[wl*LSTR2 + (ci ^ swz8(wl))] = f2bf(gelu_fast(acc8[j] + shv));
        }
    };

    ConvBuf A, Bb;
    load(A, 0);
#pragma unroll 1
    for (int it2 = 0; it2 < 2; ++it2) {
        load(Bb, it2*2 + 1);      // issue next loads, then compute current
        comp(A, it2*2);
        if (it2 < 1) load(A, it2*2 + 2);
        comp(Bb, it2*2 + 1);
    }
}

// Conv experts, fused per half-row (32 px): dwconv+BN+gelu -> feat[w32][ci]
// (16 KB LDS) -> pw GEMM -> +pb -> out.
__global__ __launch_bounds__(256) void kconv(
    const float* __restrict__ x, const int* __restrict__ idx,
    const float* __restrict__ kf0, const float* __restrict__ kf1,
    const float* __restrict__ shAll, const short* __restrict__ apackAll,
    const float* __restrict__ e0pb, const float* __restrict__ e1pb,
    float* __restrict__ out)
{
    __shared__ short lds[32*LSTR2];   // 16 KB, [wl][ci^swz]
    int h, wbase, b;
    swz_hb2(blockIdx.x, blockIdx.y, h, wbase, b);
    const int e = idx[b];
    if (e >= 2) return;
    const int t = threadIdx.x;
    const int lane = t & 63, wid = t >> 6;
    const int l15 = lane & 15, quad = lane >> 4;

    if (e == 0) conv_half_t<1>(x, kf0, shAll,     lds, b, h, wbase, t);
    else        conv_half_t<2>(x, kf1, shAll + C, lds, b, h, wbase, t);
    __syncthreads();

    // GEMM2: D[o][w32] = pw . feat ; wave wid owns o = wid*64..+63
    const short* pwf = apackAll + (size_t)e * 65536;
    f32x4 acc[4][2];
#pragma unroll
    for (int i = 0; i < 4; ++i)
#pragma unroll
        for (int wt = 0; wt < 2; ++wt) acc[i][wt] = (f32x4){0.f,0.f,0.f,0.f};
    for (int kt = 0; kt < 8; ++kt) {
        short8 bf[2];
#pragma unroll
        for (int wt = 0; wt < 2; ++wt) {
            int wl = wt*16 + l15;
            bf[wt] = *(const short8*)&lds[wl*LSTR2 + ((kt*32 + quad*8) ^ swz8(wl))];
        }
        short8 af[4];
#pragma unroll
        for (int i = 0; i < 4; ++i)
            af[i] = *(const short8*)&pwf[((size_t)(kt*16 + wid*4 + i)*64 + lane)*8];
#pragma unroll
        for (int i = 0; i < 4; ++i)
#pragma unroll
            for (int wt = 0; wt < 2; ++wt)
                acc[i][wt] = __builtin_amdgcn_mfma_f32_16x16x32_bf16(
                    af[i], bf[wt], acc[i][wt], 0, 0, 0);
    }

    const float* pb = (e == 0) ? e0pb : e1pb;
#pragma unroll
    for (int i = 0; i < 4; ++i) {
        int ob = wid*64 + i*16 + quad*4;
        float4 p4 = *(const float4*)&pb[ob];
        float pbv[4] = {p4.x, p4.y, p4.z, p4.w};
#pragma unroll
        for (int wt = 0; wt < 2; ++wt) {
            int w = wbase + wt*16 + l15;
#pragma unroll
            for (int r = 0; r < 4; ++r)
                out[((size_t)(b*C + ob + r))*HW + h*W + w] = acc[i][wt][r] + pbv[r];
        }
    }
}

// 3-product split-bf16 GEMM over [w32][ci] hi/lo LDS tiles:
// acc += Ahi*Bhi + Ahi*Blo + Alo*Bhi  (~fp32 accurate; lo*lo term ~2^-18 dropped)
__device__ __forceinline__ void gemm3t(const short* __restrict__ aH,
                                       const short* __restrict__ aL,
                                       const short* __restrict__ ldsH,
                                       const short* __restrict__ ldsL,
                                       int lane, int wid, f32x4 acc[4][2])
{
    const int l15 = lane & 15, quad = lane >> 4;
    for (int kt = 0; kt < 8; ++kt) {
        short8 bH[2], bL[2];
#pragma unroll
        for (int wt = 0; wt < 2; ++wt) {
            int wl = wt*16 + l15;
            int off = wl*LSTR2 + ((kt*32 + quad*8) ^ swz8(wl));
            bH[wt] = *(const short8*)&ldsH[off];
            bL[wt] = *(const short8*)&ldsL[off];
        }
        short8 fH[4], fL[4];
#pragma unroll
        for (int i = 0; i < 4; ++i) {
            size_t off = ((size_t)(kt*16 + wid*4 + i)*64 + lane)*8;
            fH[i] = *(const short8*)&aH[off];
            fL[i] = *(const short8*)&aL[off];
        }
#pragma unroll
        for (int i = 0; i < 4; ++i)
#pragma unroll
            for (int wt = 0; wt < 2; ++wt) {
                acc[i][wt] = __builtin_amdgcn_mfma_f32_16x16x32_bf16(fH[i], bH[wt], acc[i][wt], 0, 0, 0);
                acc[i][wt] = __builtin_amdgcn_mfma_f32_16x16x32_bf16(fH[i], bL[wt], acc[i][wt], 0, 0, 0);
                acc[i][wt] = __builtin_amdgcn_mfma_f32_16x16x32_bf16(fL[i], bH[wt], acc[i][wt], 0, 0, 0);
            }
    }
}

// e2 expert, fused per half-row (32 px): x hi/lo [w32][ci] tiles (16+16 KB) ->
// e2k GEMM (3-prod) -> BN+gelu -> feat hi/lo (overwrite) -> pw2 GEMM (3-prod)
// -> +pb -> out (fp32). ~fp32-exact e2 outputs.
__global__ __launch_bounds__(256) void ke2h(
    const float* __restrict__ x, const int* __restrict__ idx,
    const float* __restrict__ scAll, const float* __restrict__ shAll,
    const short* __restrict__ apackAll, const float* __restrict__ e2pb,
    float* __restrict__ out)
{
    __shared__ short ldsH[32*LSTR2];   // 16 KB hi tile [wl][ci^swz]
    __shared__ short ldsL[32*LSTR2];   // 16 KB lo tile
    int h, wbase, b;
    swz_hb2(blockIdx.x, blockIdx.y, h, wbase, b);
    if (idx[b] != 2) return;
    const int t = threadIdx.x;
    const int lane = t & 63, wid = t >> 6;
    const int l15 = lane & 15, quad = lane >> 4;

    // stage x half-row: lanes cover 32 consecutive w (coalesced 128B/instr)
    {
        const int wl = t & 31, g = t >> 5;     // g in 0..7
        const int vsw = swz8(wl);
#pragma unroll
        for (int k = 0; k < 4; ++k) {
            int ci0 = g*32 + k*8;
            const float* px = x + ((size_t)(b*C + ci0)*H + h)*W + wbase + wl;
            float f[8];
#pragma unroll
            for (int j = 0; j < 8; ++j) f[j] = px[(size_t)j * HW];
            short8 hi, lo;
#pragma unroll
            for (int j = 0; j < 8; ++j) {
                short hj = f2bf(f[j]);
                hi[j] = hj;
                lo[j] = f2bf(f[j] - bf2f(hj));
            }
            int col = ci0 ^ vsw;
            *(short8*)&ldsH[wl*LSTR2 + col] = hi;
            *(short8*)&ldsL[wl*LSTR2 + col] = lo;
        }
    }
    __syncthreads();

    // GEMM1: z[co][w32] = e2k @ x  (split-accurate)
    f32x4 acc[4][2];
#pragma unroll
    for (int i = 0; i < 4; ++i)
#pragma unroll
        for (int wt = 0; wt < 2; ++wt) acc[i][wt] = (f32x4){0.f,0.f,0.f,0.f};
    gemm3t(apackAll + (size_t)3*65536, apackAll + (size_t)5*65536,
           ldsH, ldsL, lane, wid, acc);
    __syncthreads();   // all waves done reading x before feat overwrites tiles

    // BN + gelu; split feat hi/lo, store [wl][co^swz]
    {
        const float* sc2 = scAll + 2*C;
        const float* sh2 = shAll + 2*C;
#pragma unroll
        for (int i = 0; i < 4; ++i) {
            int cob = wid*64 + i*16 + quad*4;
            float4 s4 = *(const float4*)&sc2[cob];
            float4 h4 = *(const float4*)&sh2[cob];
            float ss[4] = {s4.x, s4.y, s4.z, s4.w};
            float hh[4] = {h4.x, h4.y, h4.z, h4.w};
#pragma unroll
            for (int wt = 0; wt < 2; ++wt) {
                int wl = wt*16 + l15;
                int col = cob ^ swz8(wl);   // swz flips bits>=3: 4-short groups kept
                short4v ph, pl;
#pragma unroll
                for (int r = 0; r < 4; ++r) {
                    float f = gelu_fast(acc[i][wt][r]*ss[r] + hh[r]);
                    short hj = f2bf(f);
                    ph[r] = hj;
                    pl[r] = f2bf(f - bf2f(hj));
                }
                *(short4v*)&ldsH[wl*LSTR2 + col] = ph;
                *(short4v*)&ldsL[wl*LSTR2 + col] = pl;
            }
        }
    }
    __syncthreads();

    // GEMM2: out[o][w32] = pw2 @ feat  (split-accurate)
#pragma unroll
    for (int i = 0; i < 4; ++i)
#pragma unroll
        for (int wt = 0; wt < 2; ++wt) acc[i][wt] = (f32x4){0.f,0.f,0.f,0.f};
    gemm3t(apackAll + (size_t)2*65536, apackAll + (size_t)4*65536,
           ldsH, ldsL, lane, wid, acc);

    // epilogue: + pb, store fp32
#pragma unroll
    for (int i = 0; i < 4; ++i) {
        int ob = wid*64 + i*16 + quad*4;
        float4 p4 = *(const float4*)&e2pb[ob];
        float pbv[4] = {p4.x, p4.y, p4.z, p4.w};
#pragma unroll
        for (int wt = 0; wt < 2; ++wt) {
            int w = wbase + wt*16 + l15;
#pragma unroll
            for (int r = 0; r < 4; ++r)
                out[((size_t)(b*C + ob + r))*HW + h*W + w] = acc[i][wt][r] + pbv[r];
        }
    }
}

extern "C" void kernel_launch(void* const* d_in, const int* in_sizes, int n_in,
                              void* d_out, int out_size, void* d_ws, size_t ws_size,
                              hipStream_t stream) {
    const float* x    = (const float*)d_in[0];
    const float* rw   = (const float*)d_in[1];
    const float* rb   = (const float*)d_in[2];
    const float* e0k  = (const float*)d_in[3];
    const float* e0g  = (const float*)d_in[4];
    const float* e0b  = (const float*)d_in[5];
    const float* e0m  = (const float*)d_in[6];
    const float* e0v  = (const float*)d_in[7];
    const float* e0pw = (const float*)d_in[8];
    const float* e0pb = (const float*)d_in[9];
    const float* e1k  = (const float*)d_in[10];
    const float* e1g  = (const float*)d_in[11];
    const float* e1b  = (const float*)d_in[12];
    const float* e1m  = (const float*)d_in[13];
    const float* e1v  = (const float*)d_in[14];
    const float* e1pw = (const float*)d_in[15];
    const float* e1pb = (const float*)d_in[16];
    const float* e2k  = (const float*)d_in[17];
    const float* e2g  = (const float*)d_in[18];
    const float* e2b  = (const float*)d_in[19];
    const float* e2m  = (const float*)d_in[20];
    const float* e2v  = (const float*)d_in[21];
    const float* e2pw = (const float*)d_in[22];
    const float* e2pb = (const float*)d_in[23];
    float* out = (float*)d_out;

    char* wsb = (char*)d_ws;
    float* pooled   = (float*)wsb;                       // 32768 B
    int*   idx      = (int*)(wsb + 32768);               // 128 B
    float* scAll    = (float*)(wsb + 32896);             // 3072 B
    float* shAll    = (float*)(wsb + 35968);             // 3072 B
    float* kf0      = (float*)(wsb + 39040);             // 12288 B
    float* kf1      = (float*)(wsb + 51328);             // 12288 B
    short* apackAll = (short*)(wsb + 63616);             // 786432 B (6 mats)

    pool_kernel<<<B*C, 256, 0, stream>>>(x, pooled);
    prep_kernel<<<194, 256, 0, stream>>>(e0pw, e1pw, e2pw, e2k, e0k, e1k,
                                         e0g, e0b, e0m, e0v,
                                         e1g, e1b, e1m, e1v,
                                         e2g, e2b, e2m, e2v,
                                         pooled, rw, rb, idx,
                                         apackAll, kf0, kf1, scAll, shAll);
    kconv<<<dim3(2*H, B), 256, 0, stream>>>(x, idx, kf0, kf1, shAll, apackAll,
                                            e0pb, e1pb, out);
    ke2h<<<dim3(2*H, B), 256, 0, stream>>>(x, idx, scAll, shAll, apackAll,
                                           e2pb, out);
}